// Round 3
// baseline (92.347 us; speedup 1.0000x reference)
//
#include <hip/hip_runtime.h>
#include <hip/hip_bf16.h>

#define BATCH 8
#define SEQ   8192
#define DIM   512

typedef float f32x4 __attribute__((ext_vector_type(4)));

#define INV2PI   0.15915494309189535f
#define SQRT_DIM 22.62741699796952f
// -log2(10000)/256  (div[k] = 2^(C2*k) = exp(-2k*ln(10000)/512))
#define C2 (-0.05190512648261504f)

// ---------------------------------------------------------------------------
// seg_kernel: one WAVE per batch row. Lane chunk = 128 tokens. No barriers.
//
// Reference scan per step i (i=1..SEQ-1), carry nc (starts 0):
//   c=t[i]; p=t[i-1];
//   if (36<=c<=41) nc=2;
//   is_note = c<12;
//   flag = is_note ? ((p>=12)||(nc>0)) : (p<12);
//   if (is_note) nc-=1;
// seg = inclusive cumsum of flags (flag for token 0 is 0).
//
// Chunk transform of nc is (reset,val): T(nc)=reset?val:nc+val. Applied to
// nc0=0 the prefix value is just `val`. Compose(prev,cur) =
//   cur.reset ? cur : {prev.reset, prev.val+cur.val}.
// ---------------------------------------------------------------------------
#define SEG_CHUNK (SEQ / 64)   // 128

__global__ __launch_bounds__(64)
void seg_kernel(const int* __restrict__ tok, int* __restrict__ seg) {
    const int b    = blockIdx.x;
    const int lane = threadIdx.x;
    const int* t   = tok + (size_t)b * SEQ;
    int*      sg   = seg + (size_t)b * SEQ;

    const int start = lane * SEG_CHUNK;
    const int end   = start + SEG_CHUNK;
    const int lo    = (start < 1) ? 1 : start;

    // ---- pass 1: per-lane nc transform ---------------------------------
    int reset = 0, val = 0;
    #pragma unroll 8
    for (int i = lo; i < end; ++i) {
        int c = t[i];
        if (c >= 36 && c <= 41) { reset = 1; val = 2; }
        if (c < 12) val -= 1;
    }

    // wave inclusive scan of the (reset,val) monoid (6 shfl_up steps)
    #pragma unroll
    for (int off = 1; off < 64; off <<= 1) {
        int pv = __shfl_up(val, off);
        int pr = __shfl_up(reset, off);
        if (lane >= off && !reset) { val += pv; reset = pr; }
    }
    int nc_entry = __shfl_up(val, 1);
    if (lane == 0) nc_entry = 0;

    // ---- pass 2: per-lane flag count with known entry nc ----------------
    int nc = nc_entry;
    int total = 0;
    #pragma unroll 8
    for (int i = lo; i < end; ++i) {
        int c = t[i];
        int p = t[i - 1];
        if (c >= 36 && c <= 41) nc = 2;
        bool is_note = (c < 12);
        int f = is_note ? (int)((p >= 12) || (nc > 0)) : (int)(p < 12);
        if (is_note) nc -= 1;
        total += f;
    }

    // wave inclusive add-scan
    #pragma unroll
    for (int off = 1; off < 64; off <<= 1) {
        int pv = __shfl_up(total, off);
        if (lane >= off) total += pv;
    }
    int run = __shfl_up(total, 1);
    if (lane == 0) run = 0;

    // ---- pass 3: recompute flags, write inclusive cumsum ----------------
    nc = nc_entry;
    if (start == 0) sg[0] = 0;
    #pragma unroll 8
    for (int i = lo; i < end; ++i) {
        int c = t[i];
        int p = t[i - 1];
        if (c >= 36 && c <= 41) nc = 2;
        bool is_note = (c < 12);
        int f = is_note ? (int)((p >= 12) || (nc > 0)) : (int)(p < 12);
        if (is_note) nc -= 1;
        run += f;
        sg[i] = run;
    }
}

// ---------------------------------------------------------------------------
// out_kernel: out[row,d] = emb[tok[row],d]*sqrt(512) + pe(seg[row],d)
// pe(pos,2k) = sin(pos*div[k]), pe(pos,2k+1) = cos(pos*div[k]),
// div[k] = 2^(C2*k) -> one v_exp_f32 each; sin/cos in revolutions with
// explicit fract range reduction.
//
// One thread = 8 consecutive floats (2x float4). 64 threads (1 wave) = one
// 512-float row, so row/token/seg are wave-uniform -> scalar loads.
// Output is write-once: nontemporal stores.
// ---------------------------------------------------------------------------
__global__ __launch_bounds__(256)
void out_kernel(const int*   __restrict__ tok,
                const int*   __restrict__ seg,
                const float* __restrict__ emb,
                float*       __restrict__ out) {
    const long long g = (long long)blockIdx.x * 256 + threadIdx.x;
    const int row = __builtin_amdgcn_readfirstlane((int)(g >> 6)); // wave-uniform
    const int d0  = ((int)g & 63) << 3;                            // 0..504 step 8

    const int   token = tok[row];            // scalar (uniform address)
    const float segf  = (float)seg[row];

    const float4* ep = reinterpret_cast<const float4*>(emb + (size_t)token * DIM + d0);
    const float4 e0 = ep[0], e1 = ep[1];

    const float k0 = (float)(d0 >> 1);
    float pe[8];
    #pragma unroll
    for (int j = 0; j < 4; ++j) {
        const float div = __builtin_amdgcn_exp2f(C2 * (k0 + (float)j));
        float r = segf * div * INV2PI;
        r -= floorf(r);
        pe[2 * j]     = __builtin_amdgcn_sinf(r);
        pe[2 * j + 1] = __builtin_amdgcn_cosf(r);
    }

    f32x4 o0, o1;
    o0.x = e0.x * SQRT_DIM + pe[0];  o0.y = e0.y * SQRT_DIM + pe[1];
    o0.z = e0.z * SQRT_DIM + pe[2];  o0.w = e0.w * SQRT_DIM + pe[3];
    o1.x = e1.x * SQRT_DIM + pe[4];  o1.y = e1.y * SQRT_DIM + pe[5];
    o1.z = e1.z * SQRT_DIM + pe[6];  o1.w = e1.w * SQRT_DIM + pe[7];

    f32x4* op = reinterpret_cast<f32x4*>(out + (size_t)row * DIM + d0);
    __builtin_nontemporal_store(o0, op);
    __builtin_nontemporal_store(o1, op + 1);
}

extern "C" void kernel_launch(void* const* d_in, const int* in_sizes, int n_in,
                              void* d_out, int out_size, void* d_ws, size_t ws_size,
                              hipStream_t stream) {
    const int*   tok = (const int*)d_in[0];     // (BATCH, SEQ) int32
    const float* emb = (const float*)d_in[1];   // (VOCAB, DIM) f32
    float*       out = (float*)d_out;           // (BATCH, SEQ, DIM) f32
    int*         seg = (int*)d_ws;              // (BATCH, SEQ) int32 scratch

    seg_kernel<<<BATCH, 64, 0, stream>>>(tok, seg);

    // BATCH*SEQ rows * 64 threads/row / 256 threads/block = 16384 blocks
    const int blocks = (int)((long long)BATCH * SEQ * 64 / 256);
    out_kernel<<<blocks, 256, 0, stream>>>(tok, seg, emb, out);
}

// Round 4
// 55.172 us; speedup vs baseline: 1.6738x; 1.6738x over previous
//
#include <hip/hip_runtime.h>
#include <hip/hip_bf16.h>

#define BATCH 8
#define SEQ   8192
#define DIM   512

typedef float f32x4 __attribute__((ext_vector_type(4)));

#define INV2PI   0.15915494309189535f
#define SQRT_DIM 22.62741699796952f
// -log2(10000)/256  (div[k] = 2^(C2*k) = exp(-2k*ln(10000)/512))
#define C2 (-0.05190512648261504f)

// Workspace: [0,256KB) seg ids, [256KB, +16MB) pe table
#define SEG_BYTES ((size_t)BATCH * SEQ * 4)
#define PE_BYTES  ((size_t)SEQ * DIM * 4)

#define SEG_BLOCKS BATCH
#define PE_TPB     256
#define PE_FLOATS  8
#define PE_BLOCKS  ((SEQ * DIM) / (PE_TPB * PE_FLOAT_CNT))
#define PE_FLOAT_CNT 8
#undef PE_BLOCKS
#define PE_BLOCKS  ((SEQ * DIM) / (PE_TPB * PE_FLOAT_CNT))   // 2048

// LDS token index with +1-per-32 padding: bank = (lane + j) & 31 -> 2-way, free
#define TIDX(k) ((k) + ((k) >> 5))
#define CHUNK 32            // tokens per thread (8192 / 256)

// ---------------------------------------------------------------------------
// prep_kernel
//   blocks [0, 8)        : segment-id scan, one block per batch row
//   blocks [8, 8+2048)   : pe table fill
//
// seg reference (step i = 1..SEQ-1, carry nc starts 0):
//   c=t[i]; p=t[i-1];
//   if (36<=c<=41) nc=2;
//   is_note = c<12;
//   flag = is_note ? ((p>=12)||(nc>0)) : (p<12);
//   if (is_note) nc-=1;
//   seg = inclusive cumsum of flags (flag for token 0 = 0)
//
// nc chunk transform (reset,val): T(nc)=reset?val:nc+val; applied to nc=0 the
// prefix value is just val. compose(earlier A, later B) =
//   B.reset ? B : {A.reset, A.val+B.val}.
// ---------------------------------------------------------------------------
__global__ __launch_bounds__(256)
void prep_kernel(const int* __restrict__ tok, int* __restrict__ seg,
                 float* __restrict__ pe) {
    if (blockIdx.x >= SEG_BLOCKS) {
        // ------------------------- pe table fill -------------------------
        const int g    = (int)(blockIdx.x - SEG_BLOCKS) * PE_TPB + threadIdx.x;
        const int base = g << 3;                 // first of 8 floats
        const float pos = (float)(base >> 9);    // base / DIM
        const int d0   = base & (DIM - 1);
        const float k0 = (float)(d0 >> 1);

        float v[8];
        #pragma unroll
        for (int j = 0; j < 4; ++j) {
            const float div = __builtin_amdgcn_exp2f(C2 * (k0 + (float)j));
            float r = pos * div * INV2PI;
            r -= floorf(r);
            v[2 * j]     = __builtin_amdgcn_sinf(r);
            v[2 * j + 1] = __builtin_amdgcn_cosf(r);
        }
        f32x4* pp = reinterpret_cast<f32x4*>(pe + (size_t)base);
        pp[0] = (f32x4){v[0], v[1], v[2], v[3]};
        pp[1] = (f32x4){v[4], v[5], v[6], v[7]};
        return;
    }

    // --------------------------- segment scan ----------------------------
    __shared__ int s_tok[SEQ + SEQ / 32];   // 33 KB, padded
    __shared__ int s_seg[SEQ + SEQ / 32];   // 33 KB, padded
    __shared__ int s_pr[4], s_pv[4], s_cnt[4];

    const int b    = blockIdx.x;
    const int tid  = threadIdx.x;
    const int lane = tid & 63;
    const int wv   = tid >> 6;
    const int* t   = tok + (size_t)b * SEQ;
    int*      sg   = seg + (size_t)b * SEQ;

    // stage tokens coalesced into LDS
    #pragma unroll
    for (int m = 0; m < CHUNK; ++m) {
        const int k = m * 256 + tid;
        s_tok[TIDX(k)] = t[k];
    }
    __syncthreads();

    const int start = tid * CHUNK;
    const int end   = start + CHUNK;
    const int lo    = (start < 1) ? 1 : start;

    // ---- pass 1: per-thread nc transform --------------------------------
    int reset = 0, val = 0;
    for (int i = lo; i < end; ++i) {
        const int c = s_tok[TIDX(i)];
        if (c >= 36 && c <= 41) { reset = 1; val = 2; }
        if (c < 12) val -= 1;
    }

    // wave-inclusive monoid scan
    int ir = reset, iv = val;
    #pragma unroll
    for (int off = 1; off < 64; off <<= 1) {
        const int pv = __shfl_up(iv, off);
        const int pr = __shfl_up(ir, off);
        if (lane >= off && !ir) { iv += pv; ir = pr; }
    }
    // lane-exclusive
    int er = __shfl_up(ir, 1), ev = __shfl_up(iv, 1);
    if (lane == 0) { er = 0; ev = 0; }
    if (lane == 63) { s_pr[wv] = ir; s_pv[wv] = iv; }
    __syncthreads();
    // block-exclusive prefix over wave totals (in order)
    int br = 0, bv = 0;
    for (int w = 0; w < wv; ++w) {
        const int r2 = s_pr[w], v2 = s_pv[w];
        if (r2) { br = 1; bv = v2; } else { bv += v2; }
    }
    // entry transform = compose(block_prefix, lane_exclusive), applied to 0
    const int nc_entry = er ? ev : (bv + ev);

    // ---- pass 2: per-thread flag count ----------------------------------
    int nc = nc_entry, total = 0;
    for (int i = lo; i < end; ++i) {
        const int c = s_tok[TIDX(i)];
        const int p = s_tok[TIDX(i - 1)];
        if (c >= 36 && c <= 41) nc = 2;
        const bool is_note = (c < 12);
        const int f = is_note ? (int)((p >= 12) || (nc > 0)) : (int)(p < 12);
        if (is_note) nc -= 1;
        total += f;
    }

    int it = total;
    #pragma unroll
    for (int off = 1; off < 64; off <<= 1) {
        const int pv = __shfl_up(it, off);
        if (lane >= off) it += pv;
    }
    int et = __shfl_up(it, 1);
    if (lane == 0) et = 0;
    if (lane == 63) s_cnt[wv] = it;
    __syncthreads();
    int boff = 0;
    for (int w = 0; w < wv; ++w) boff += s_cnt[w];
    int run = boff + et;

    // ---- pass 3: recompute flags, cumsum into LDS, flush coalesced ------
    nc = nc_entry;
    if (start == 0) s_seg[TIDX(0)] = 0;
    for (int i = lo; i < end; ++i) {
        const int c = s_tok[TIDX(i)];
        const int p = s_tok[TIDX(i - 1)];
        if (c >= 36 && c <= 41) nc = 2;
        const bool is_note = (c < 12);
        const int f = is_note ? (int)((p >= 12) || (nc > 0)) : (int)(p < 12);
        if (is_note) nc -= 1;
        run += f;
        s_seg[TIDX(i)] = run;
    }
    __syncthreads();
    #pragma unroll
    for (int m = 0; m < CHUNK; ++m) {
        const int k = m * 256 + tid;
        sg[k] = s_seg[TIDX(k)];
    }
}

// ---------------------------------------------------------------------------
// out_kernel: out[row,d] = emb[tok[row],d]*sqrt(512) + pe[seg[row],d]
// 64 threads (1 wave) per 512-float row -> tok/seg wave-uniform.
// One thread = 8 consecutive floats (2x float4). Plain stores.
// ---------------------------------------------------------------------------
__global__ __launch_bounds__(256)
void out_kernel(const int*   __restrict__ tok,
                const int*   __restrict__ seg,
                const float* __restrict__ emb,
                const float* __restrict__ pe,
                float*       __restrict__ out) {
    const long long g = (long long)blockIdx.x * 256 + threadIdx.x;
    const int row = (int)(g >> 6);
    const int d0  = ((int)g & 63) << 3;

    const int token = tok[row];
    const int sgv   = seg[row];

    const f32x4* ep = reinterpret_cast<const f32x4*>(emb + (size_t)token * DIM + d0);
    const f32x4* pp = reinterpret_cast<const f32x4*>(pe  + (size_t)sgv   * DIM + d0);
    const f32x4 e0 = ep[0], e1 = ep[1];
    const f32x4 p0 = pp[0], p1 = pp[1];

    f32x4 o0, o1;
    o0.x = e0.x * SQRT_DIM + p0.x;  o0.y = e0.y * SQRT_DIM + p0.y;
    o0.z = e0.z * SQRT_DIM + p0.z;  o0.w = e0.w * SQRT_DIM + p0.w;
    o1.x = e1.x * SQRT_DIM + p1.x;  o1.y = e1.y * SQRT_DIM + p1.y;
    o1.z = e1.z * SQRT_DIM + p1.z;  o1.w = e1.w * SQRT_DIM + p1.w;

    f32x4* op = reinterpret_cast<f32x4*>(out + (size_t)row * DIM + d0);
    op[0] = o0;
    op[1] = o1;
}

// ---------------------------------------------------------------------------
// Fallback out (ws too small for pe table): inline trig, plain stores.
// ---------------------------------------------------------------------------
__global__ __launch_bounds__(256)
void out_kernel_trig(const int*   __restrict__ tok,
                     const int*   __restrict__ seg,
                     const float* __restrict__ emb,
                     float*       __restrict__ out) {
    const long long g = (long long)blockIdx.x * 256 + threadIdx.x;
    const int row = (int)(g >> 6);
    const int d0  = ((int)g & 63) << 3;

    const int   token = tok[row];
    const float segf  = (float)seg[row];

    const f32x4* ep = reinterpret_cast<const f32x4*>(emb + (size_t)token * DIM + d0);
    const f32x4 e0 = ep[0], e1 = ep[1];

    const float k0 = (float)(d0 >> 1);
    float pv[8];
    #pragma unroll
    for (int j = 0; j < 4; ++j) {
        const float div = __builtin_amdgcn_exp2f(C2 * (k0 + (float)j));
        float r = segf * div * INV2PI;
        r -= floorf(r);
        pv[2 * j]     = __builtin_amdgcn_sinf(r);
        pv[2 * j + 1] = __builtin_amdgcn_cosf(r);
    }

    f32x4 o0, o1;
    o0.x = e0.x * SQRT_DIM + pv[0];  o0.y = e0.y * SQRT_DIM + pv[1];
    o0.z = e0.z * SQRT_DIM + pv[2];  o0.w = e0.w * SQRT_DIM + pv[3];
    o1.x = e1.x * SQRT_DIM + pv[4];  o1.y = e1.y * SQRT_DIM + pv[5];
    o1.z = e1.z * SQRT_DIM + pv[6];  o1.w = e1.w * SQRT_DIM + pv[7];

    f32x4* op = reinterpret_cast<f32x4*>(out + (size_t)row * DIM + d0);
    op[0] = o0;
    op[1] = o1;
}

extern "C" void kernel_launch(void* const* d_in, const int* in_sizes, int n_in,
                              void* d_out, int out_size, void* d_ws, size_t ws_size,
                              hipStream_t stream) {
    const int*   tok = (const int*)d_in[0];     // (BATCH, SEQ) int32
    const float* emb = (const float*)d_in[1];   // (VOCAB, DIM) f32
    float*       out = (float*)d_out;           // (BATCH, SEQ, DIM) f32
    int*         seg = (int*)d_ws;
    float*       pe  = (float*)((char*)d_ws + SEG_BYTES);

    const bool have_pe_ws = (ws_size >= SEG_BYTES + PE_BYTES);
    const int  out_blocks = (int)((long long)BATCH * SEQ * 64 / 256);  // 16384

    if (have_pe_ws) {
        prep_kernel<<<SEG_BLOCKS + PE_BLOCKS, 256, 0, stream>>>(tok, seg, pe);
        out_kernel<<<out_blocks, 256, 0, stream>>>(tok, seg, emb, pe, out);
    } else {
        prep_kernel<<<SEG_BLOCKS, 256, 0, stream>>>(tok, seg, pe);
        out_kernel_trig<<<out_blocks, 256, 0, stream>>>(tok, seg, emb, out);
    }
}

// Round 5
// 44.980 us; speedup vs baseline: 2.0531x; 1.2266x over previous
//
#include <hip/hip_runtime.h>
#include <hip/hip_bf16.h>

#define BATCH 8
#define SEQ   8192
#define DIM   512

typedef float f32x4 __attribute__((ext_vector_type(4)));

#define INV2PI   0.15915494309189535f
#define SQRT_DIM 22.62741699796952f
// -log2(10000)/256  (div[k] = 2^(C2*k) = exp(-2k*ln(10000)/512))
#define C2 (-0.05190512648261504f)

// Workspace: [0,256KB) seg ids, [256KB, +16MB) pe table
#define SEG_BYTES ((size_t)BATCH * SEQ * 4)
#define PE_BYTES  ((size_t)SEQ * DIM * 4)

#define TPB_PREP  1024
#define SEG_CHUNK (SEQ / TPB_PREP)        // 8 tokens / thread
#define NWAVE     (TPB_PREP / 64)         // 16
#define PE_ROWS_PER_BLOCK (TPB_PREP / 64) // 16 rows (1 wave = 1 row)
#define PE_BLOCKS (SEQ / PE_ROWS_PER_BLOCK) // 512

// LDS index, +1 int per 8: bank = (9t+j)&31 -> only 2-way (lane vs lane+32) = free
#define TIX(k) ((k) + ((k) >> 3))

// ---------------------------------------------------------------------------
// prep_kernel
//   blocks [0,8)       : segment-id scan, one block (1024 thr) per batch row
//   blocks [8,8+512)   : pe table fill, 16 rows per block, lane-contiguous
//
// seg reference (step i = 1..SEQ-1, carry nc starts 0):
//   c=t[i]; p=t[i-1];
//   if (36<=c<=41) nc=2;
//   is_note = c<12;
//   flag = is_note ? ((p>=12)||(nc>0)) : (p<12);
//   if (is_note) nc-=1;
//   seg = inclusive cumsum of flags (flag for token 0 = 0)
//
// nc chunk transform (reset,val): T(nc)=reset?val:nc+val; applied to nc=0 the
// prefix value is just val. compose(earlier A, later B) =
//   B.reset ? B : {A.reset, A.val+B.val}.
// ---------------------------------------------------------------------------
__global__ __launch_bounds__(TPB_PREP)
void prep_kernel(const int* __restrict__ tok, int* __restrict__ seg,
                 float* __restrict__ pe) {
    const int tid  = threadIdx.x;
    const int lane = tid & 63;
    const int wv   = tid >> 6;

    if (blockIdx.x >= BATCH) {
        // ------------------------- pe table fill -------------------------
        const int pos = ((int)blockIdx.x - BATCH) * PE_ROWS_PER_BLOCK + wv;
        const float posf = (float)pos;
        const int dA = lane << 2;        // floats [dA, dA+4)
        const int dB = dA + 256;         // floats [dB, dB+4)

        float vA[4], vB[4];
        #pragma unroll
        for (int j = 0; j < 2; ++j) {
            const float kA = (float)((dA >> 1) + j);
            const float divA = __builtin_amdgcn_exp2f(C2 * kA);
            float rA = posf * divA * INV2PI;  rA -= floorf(rA);
            vA[2 * j]     = __builtin_amdgcn_sinf(rA);
            vA[2 * j + 1] = __builtin_amdgcn_cosf(rA);

            const float kB = (float)((dB >> 1) + j);
            const float divB = __builtin_amdgcn_exp2f(C2 * kB);
            float rB = posf * divB * INV2PI;  rB -= floorf(rB);
            vB[2 * j]     = __builtin_amdgcn_sinf(rB);
            vB[2 * j + 1] = __builtin_amdgcn_cosf(rB);
        }
        float* prow = pe + (size_t)pos * DIM;
        *reinterpret_cast<f32x4*>(prow + dA) = (f32x4){vA[0], vA[1], vA[2], vA[3]};
        *reinterpret_cast<f32x4*>(prow + dB) = (f32x4){vB[0], vB[1], vB[2], vB[3]};
        return;
    }

    // --------------------------- segment scan ----------------------------
    __shared__ int s_tok[SEQ + SEQ / 8];   // 36 KB
    __shared__ int s_seg[SEQ + SEQ / 8];   // 36 KB
    __shared__ int s_pr[NWAVE], s_pv[NWAVE], s_cnt[NWAVE];

    const int b  = blockIdx.x;
    const int* t = tok + (size_t)b * SEQ;
    int*      sg = seg + (size_t)b * SEQ;

    // stage tokens coalesced into LDS
    #pragma unroll
    for (int m = 0; m < SEG_CHUNK; ++m) {
        const int k = m * TPB_PREP + tid;
        s_tok[TIX(k)] = t[k];
    }
    __syncthreads();

    const int start = tid * SEG_CHUNK;
    const int end   = start + SEG_CHUNK;
    const int lo    = (start < 1) ? 1 : start;

    // ---- pass 1: per-thread nc transform --------------------------------
    int reset = 0, val = 0;
    #pragma unroll
    for (int i = lo; i < end; ++i) {
        const int c = s_tok[TIX(i)];
        if (c >= 36 && c <= 41) { reset = 1; val = 2; }
        if (c < 12) val -= 1;
    }

    // wave-inclusive monoid scan
    int ir = reset, iv = val;
    #pragma unroll
    for (int off = 1; off < 64; off <<= 1) {
        const int pv = __shfl_up(iv, off);
        const int pr = __shfl_up(ir, off);
        if (lane >= off && !ir) { iv += pv; ir = pr; }
    }
    int er = __shfl_up(ir, 1), ev = __shfl_up(iv, 1);
    if (lane == 0) { er = 0; ev = 0; }
    if (lane == 63) { s_pr[wv] = ir; s_pv[wv] = iv; }
    __syncthreads();
    // block-exclusive prefix over wave totals (composed in order)
    int bv = 0;
    for (int w = 0; w < wv; ++w) {
        const int r2 = s_pr[w], v2 = s_pv[w];
        if (r2) bv = v2; else bv += v2;
    }
    const int nc_entry = er ? ev : (bv + ev);

    // ---- pass 2: per-thread flag count ----------------------------------
    int nc = nc_entry, total = 0;
    #pragma unroll
    for (int i = lo; i < end; ++i) {
        const int c = s_tok[TIX(i)];
        const int p = s_tok[TIX(i - 1)];
        if (c >= 36 && c <= 41) nc = 2;
        const bool is_note = (c < 12);
        const int f = is_note ? (int)((p >= 12) || (nc > 0)) : (int)(p < 12);
        if (is_note) nc -= 1;
        total += f;
    }

    int it = total;
    #pragma unroll
    for (int off = 1; off < 64; off <<= 1) {
        const int pv = __shfl_up(it, off);
        if (lane >= off) it += pv;
    }
    int et = __shfl_up(it, 1);
    if (lane == 0) et = 0;
    if (lane == 63) s_cnt[wv] = it;
    __syncthreads();
    int boff = 0;
    for (int w = 0; w < wv; ++w) boff += s_cnt[w];
    int run = boff + et;

    // ---- pass 3: recompute flags, cumsum into LDS, flush coalesced ------
    nc = nc_entry;
    if (start == 0) s_seg[TIX(0)] = 0;
    #pragma unroll
    for (int i = lo; i < end; ++i) {
        const int c = s_tok[TIX(i)];
        const int p = s_tok[TIX(i - 1)];
        if (c >= 36 && c <= 41) nc = 2;
        const bool is_note = (c < 12);
        const int f = is_note ? (int)((p >= 12) || (nc > 0)) : (int)(p < 12);
        if (is_note) nc -= 1;
        run += f;
        s_seg[TIX(i)] = run;
    }
    __syncthreads();
    #pragma unroll
    for (int m = 0; m < SEG_CHUNK; ++m) {
        const int k = m * TPB_PREP + tid;
        sg[k] = s_seg[TIX(k)];
    }
}

// ---------------------------------------------------------------------------
// out_kernel: out[row,d] = emb[tok[row],d]*sqrt(512) + pe[seg[row],d]
//
// 1 wave = 1 row. Lane-contiguous float4s: lane covers floats [4L,4L+4) and
// [256+4L,256+4L+4) -> every load/store instruction is one dense 1KB burst.
// XCD slab swizzle: consecutive rows (which share pe rows) stay on one XCD's
// L2. tok/seg read via scalar loads (wave-uniform row). Nontemporal stores:
// write-once output, keep L2 clean for pe.
// ---------------------------------------------------------------------------
#define OUT_BLOCKS ((BATCH * SEQ) / 4)   // 4 rows per 256-thread block = 16384

__global__ __launch_bounds__(256)
void out_kernel(const int*   __restrict__ tok,
                const int*   __restrict__ seg,
                const float* __restrict__ emb,
                const float* __restrict__ pe,
                float*       __restrict__ out) {
    // bijective slab swizzle: 16384 = 8 * 2048
    const int bid = (int)blockIdx.x;
    const int vb  = ((bid & 7) << 11) | (bid >> 3);

    const int lane = (int)threadIdx.x & 63;
    const int row  = __builtin_amdgcn_readfirstlane(vb * 4 + ((int)threadIdx.x >> 6));

    const int token = tok[row];   // scalar load (uniform)
    const int sgv   = seg[row];   // scalar load (uniform)

    const int dA = lane << 2;
    const int dB = dA + 256;

    const float* erow = emb + (size_t)token * DIM;
    const float* prow = pe  + (size_t)sgv   * DIM;

    const f32x4 eA = *reinterpret_cast<const f32x4*>(erow + dA);
    const f32x4 eB = *reinterpret_cast<const f32x4*>(erow + dB);
    const f32x4 pA = *reinterpret_cast<const f32x4*>(prow + dA);
    const f32x4 pB = *reinterpret_cast<const f32x4*>(prow + dB);

    f32x4 oA, oB;
    oA.x = eA.x * SQRT_DIM + pA.x;  oA.y = eA.y * SQRT_DIM + pA.y;
    oA.z = eA.z * SQRT_DIM + pA.z;  oA.w = eA.w * SQRT_DIM + pA.w;
    oB.x = eB.x * SQRT_DIM + pB.x;  oB.y = eB.y * SQRT_DIM + pB.y;
    oB.z = eB.z * SQRT_DIM + pB.z;  oB.w = eB.w * SQRT_DIM + pB.w;

    float* orow = out + (size_t)row * DIM;
    __builtin_nontemporal_store(oA, reinterpret_cast<f32x4*>(orow + dA));
    __builtin_nontemporal_store(oB, reinterpret_cast<f32x4*>(orow + dB));
}

// ---------------------------------------------------------------------------
// Fallback out (ws too small for pe table): inline trig, same layout.
// ---------------------------------------------------------------------------
__global__ __launch_bounds__(256)
void out_kernel_trig(const int*   __restrict__ tok,
                     const int*   __restrict__ seg,
                     const float* __restrict__ emb,
                     float*       __restrict__ out) {
    const int bid = (int)blockIdx.x;
    const int vb  = ((bid & 7) << 11) | (bid >> 3);

    const int lane = (int)threadIdx.x & 63;
    const int row  = __builtin_amdgcn_readfirstlane(vb * 4 + ((int)threadIdx.x >> 6));

    const int   token = tok[row];
    const float segf  = (float)seg[row];

    const int dA = lane << 2;
    const int dB = dA + 256;

    const float* erow = emb + (size_t)token * DIM;
    const f32x4 eA = *reinterpret_cast<const f32x4*>(erow + dA);
    const f32x4 eB = *reinterpret_cast<const f32x4*>(erow + dB);

    float vA[4], vB[4];
    #pragma unroll
    for (int j = 0; j < 2; ++j) {
        const float kA = (float)((dA >> 1) + j);
        const float divA = __builtin_amdgcn_exp2f(C2 * kA);
        float rA = segf * divA * INV2PI;  rA -= floorf(rA);
        vA[2 * j]     = __builtin_amdgcn_sinf(rA);
        vA[2 * j + 1] = __builtin_amdgcn_cosf(rA);

        const float kB = (float)((dB >> 1) + j);
        const float divB = __builtin_amdgcn_exp2f(C2 * kB);
        float rB = segf * divB * INV2PI;  rB -= floorf(rB);
        vB[2 * j]     = __builtin_amdgcn_sinf(rB);
        vB[2 * j + 1] = __builtin_amdgcn_cosf(rB);
    }

    f32x4 oA, oB;
    oA.x = eA.x * SQRT_DIM + vA[0];  oA.y = eA.y * SQRT_DIM + vA[1];
    oA.z = eA.z * SQRT_DIM + vA[2];  oA.w = eA.w * SQRT_DIM + vA[3];
    oB.x = eB.x * SQRT_DIM + vB[0];  oB.y = eB.y * SQRT_DIM + vB[1];
    oB.z = eB.z * SQRT_DIM + vB[2];  oB.w = eB.w * SQRT_DIM + vB[3];

    float* orow = out + (size_t)row * DIM;
    __builtin_nontemporal_store(oA, reinterpret_cast<f32x4*>(orow + dA));
    __builtin_nontemporal_store(oB, reinterpret_cast<f32x4*>(orow + dB));
}

extern "C" void kernel_launch(void* const* d_in, const int* in_sizes, int n_in,
                              void* d_out, int out_size, void* d_ws, size_t ws_size,
                              hipStream_t stream) {
    const int*   tok = (const int*)d_in[0];     // (BATCH, SEQ) int32
    const float* emb = (const float*)d_in[1];   // (VOCAB, DIM) f32
    float*       out = (float*)d_out;           // (BATCH, SEQ, DIM) f32
    int*         seg = (int*)d_ws;
    float*       pe  = (float*)((char*)d_ws + SEG_BYTES);

    const bool have_pe_ws = (ws_size >= SEG_BYTES + PE_BYTES);

    if (have_pe_ws) {
        prep_kernel<<<BATCH + PE_BLOCKS, TPB_PREP, 0, stream>>>(tok, seg, pe);
        out_kernel<<<OUT_BLOCKS, 256, 0, stream>>>(tok, seg, emb, pe, out);
    } else {
        prep_kernel<<<BATCH, TPB_PREP, 0, stream>>>(tok, seg, pe);
        out_kernel_trig<<<OUT_BLOCKS, 256, 0, stream>>>(tok, seg, emb, out);
    }
}